// Round 1
// baseline (138.553 us; speedup 1.0000x reference)
//
#include <hip/hip_runtime.h>

#define R_ 4
#define S_ 8
#define N_ 4096
#define D_ 64

typedef __attribute__((ext_vector_type(8))) short bf16x8;
typedef __attribute__((ext_vector_type(4))) float f32x4;

__device__ __forceinline__ unsigned short f2bf(float f) {
    unsigned int u = __float_as_uint(f);
    u = (u + 0x7FFFu + ((u >> 16) & 1u)) >> 16;   // RNE truncate to bf16
    return (unsigned short)u;
}

// Kernel 1: ycombT[r][o][k] = bf16( coef[r] * sum_d x[r][k][d] * fc_w[r][o][d] )
// Layout transposed (o-major, k contiguous) so GEMM B-frag loads are 16B contiguous.
__global__ __launch_bounds__(256) void prep_kernel(
    const float* __restrict__ theta, const float* __restrict__ tt,
    const float* __restrict__ x, const float* __restrict__ fc_w,
    unsigned short* __restrict__ ycombT) {
    int r  = blockIdx.x >> 6;     // 4 relations
    int kb = blockIdx.x & 63;     // 64 k-blocks of 64
    int tid = threadIdx.x;

    __shared__ float xs[64][64];
    __shared__ float ws[64][65];  // +1 pad: (o*65+d)%32 = (o+d)%32 -> 2-way max (free)

    const float* xp = x    + ((size_t)r * N_ + (size_t)kb * 64) * D_;
    const float* wp = fc_w + (size_t)r * D_ * D_;
    for (int i = 0; i < 16; ++i) {
        int flat = i * 256 + tid;
        xs[flat >> 6][flat & 63] = xp[flat];
        ws[flat >> 6][flat & 63] = wp[flat];
    }
    float coef = 0.f;
#pragma unroll
    for (int s = 0; s < S_; ++s) coef += theta[r * S_ + s] * tt[r * S_ + s];
    __syncthreads();

    int o = tid & 63, kg = tid >> 6;
    for (int kl = kg; kl < 64; kl += 4) {
        float dot = 0.f;
#pragma unroll
        for (int d = 0; d < D_; ++d) dot += xs[kl][d] * ws[o][d];
        ycombT[(size_t)(r * D_ + o) * N_ + (size_t)kb * 64 + kl] = f2bf(coef * dot);
    }
}

// Kernel 2: per 16-row slab, wave w = relation r.
// diff[r] = prelu(a[r] @ ycombT[r]^T + fc_b[r]);  latent[s] = prelu(sum_r cw[s][r]*diff[r] + cb[s])
__global__ __launch_bounds__(256) void main_kernel(
    const float* __restrict__ a, const unsigned short* __restrict__ ycombT,
    const float* __restrict__ fc_b, const float* __restrict__ conv_w,
    const float* __restrict__ conv_b, const float* __restrict__ alpha0p,
    const float* __restrict__ alpha1p, float* __restrict__ out) {
    int rb   = blockIdx.x;            // 256 slabs of 16 rows
    int w    = threadIdx.x >> 6;      // wave = relation (and later: output channel s)
    int lane = threadIdx.x & 63;
    int l15  = lane & 15;             // A row within tile / B,D col within tile
    int kg   = lane >> 4;             // k-group

    const float* arow = a + ((size_t)(w * N_ + rb * 16 + l15)) * N_ + kg * 8;
    const unsigned short* yb = ycombT + (size_t)w * D_ * N_ + kg * 8;
    const unsigned short* b0 = yb + (size_t)(0 * 16 + l15) * N_;
    const unsigned short* b1 = yb + (size_t)(1 * 16 + l15) * N_;
    const unsigned short* b2 = yb + (size_t)(2 * 16 + l15) * N_;
    const unsigned short* b3 = yb + (size_t)(3 * 16 + l15) * N_;

    f32x4 acc0 = {0.f, 0.f, 0.f, 0.f};
    f32x4 acc1 = {0.f, 0.f, 0.f, 0.f};
    f32x4 acc2 = {0.f, 0.f, 0.f, 0.f};
    f32x4 acc3 = {0.f, 0.f, 0.f, 0.f};

#pragma unroll 4
    for (int k0 = 0; k0 < N_; k0 += 32) {
        float4 af0 = *(const float4*)(arow + k0);
        float4 af1 = *(const float4*)(arow + k0 + 4);
        bf16x8 afr;
        afr[0] = (short)f2bf(af0.x); afr[1] = (short)f2bf(af0.y);
        afr[2] = (short)f2bf(af0.z); afr[3] = (short)f2bf(af0.w);
        afr[4] = (short)f2bf(af1.x); afr[5] = (short)f2bf(af1.y);
        afr[6] = (short)f2bf(af1.z); afr[7] = (short)f2bf(af1.w);
        bf16x8 bv0 = *(const bf16x8*)(b0 + k0);
        bf16x8 bv1 = *(const bf16x8*)(b1 + k0);
        bf16x8 bv2 = *(const bf16x8*)(b2 + k0);
        bf16x8 bv3 = *(const bf16x8*)(b3 + k0);
        acc0 = __builtin_amdgcn_mfma_f32_16x16x32_bf16(afr, bv0, acc0, 0, 0, 0);
        acc1 = __builtin_amdgcn_mfma_f32_16x16x32_bf16(afr, bv1, acc1, 0, 0, 0);
        acc2 = __builtin_amdgcn_mfma_f32_16x16x32_bf16(afr, bv2, acc2, 0, 0, 0);
        acc3 = __builtin_amdgcn_mfma_f32_16x16x32_bf16(afr, bv3, acc3, 0, 0, 0);
    }

    // Epilogue. C/D layout (verified m89): col = c*16 + (lane&15), row = (lane>>4)*4 + j
    const float alpha0 = *alpha0p;
    const float alpha1 = *alpha1p;
    __shared__ float diff_s[R_][16][64];
    const float* fcb = fc_b + w * D_;
    const size_t diff_off = (size_t)R_ * N_ * D_;   // out = [latent | diffusions]

#pragma unroll
    for (int c = 0; c < 4; ++c) {
        f32x4 acc = (c == 0) ? acc0 : (c == 1) ? acc1 : (c == 2) ? acc2 : acc3;
#pragma unroll
        for (int j = 0; j < 4; ++j) {
            int col  = c * 16 + l15;
            int rloc = kg * 4 + j;
            float v = acc[j] + fcb[col];
            v = (v >= 0.f) ? v : alpha0 * v;
            diff_s[w][rloc][col] = v;
            out[diff_off + ((size_t)(w * N_ + rb * 16 + rloc)) * D_ + col] = v;
        }
    }
    __syncthreads();

    // wave w now plays output channel s = w for the 1x1 conv
    float cw0 = conv_w[w * R_ + 0], cw1 = conv_w[w * R_ + 1];
    float cw2 = conv_w[w * R_ + 2], cw3 = conv_w[w * R_ + 3];
    float cb  = conv_b[w];
#pragma unroll
    for (int c = 0; c < 4; ++c) {
#pragma unroll
        for (int j = 0; j < 4; ++j) {
            int col  = c * 16 + l15;
            int rloc = kg * 4 + j;
            float v = cb + cw0 * diff_s[0][rloc][col] + cw1 * diff_s[1][rloc][col]
                         + cw2 * diff_s[2][rloc][col] + cw3 * diff_s[3][rloc][col];
            v = (v >= 0.f) ? v : alpha1 * v;
            out[((size_t)(w * N_ + rb * 16 + rloc)) * D_ + col] = v;
        }
    }
}

extern "C" void kernel_launch(void* const* d_in, const int* in_sizes, int n_in,
                              void* d_out, int out_size, void* d_ws, size_t ws_size,
                              hipStream_t stream) {
    const float* theta  = (const float*)d_in[0];
    const float* tt     = (const float*)d_in[1];
    const float* a      = (const float*)d_in[2];
    const float* x      = (const float*)d_in[3];
    const float* fc_w   = (const float*)d_in[4];
    const float* fc_b   = (const float*)d_in[5];
    const float* conv_w = (const float*)d_in[6];
    const float* conv_b = (const float*)d_in[7];
    const float* alpha0 = (const float*)d_in[8];
    const float* alpha1 = (const float*)d_in[9];
    float* out = (float*)d_out;
    unsigned short* ycombT = (unsigned short*)d_ws;   // 4*64*4096 bf16 = 2 MiB

    prep_kernel<<<dim3(R_ * (N_ / 64)), dim3(256), 0, stream>>>(theta, tt, x, fc_w, ycombT);
    main_kernel<<<dim3(N_ / 16), dim3(256), 0, stream>>>(a, ycombT, fc_b, conv_w, conv_b,
                                                         alpha0, alpha1, out);
}

// Round 2
// 111.953 us; speedup vs baseline: 1.2376x; 1.2376x over previous
//
#include <hip/hip_runtime.h>

#define R_ 4
#define S_ 8
#define N_ 4096
#define D_ 64

typedef __attribute__((ext_vector_type(8))) short bf16x8;
typedef __attribute__((ext_vector_type(4))) float f32x4;

__device__ __forceinline__ unsigned short f2bf(float f) {
    unsigned int u = __float_as_uint(f);
    u = (u + 0x7FFFu + ((u >> 16) & 1u)) >> 16;   // RNE to bf16
    return (unsigned short)u;
}

// Kernel 1: ycombT[r][o][k] = bf16( coef[r] * sum_d x[r][k][d] * fc_w[r][o][d] )
__global__ __launch_bounds__(256) void prep_kernel(
    const float* __restrict__ theta, const float* __restrict__ tt,
    const float* __restrict__ x, const float* __restrict__ fc_w,
    unsigned short* __restrict__ ycombT) {
    int r  = blockIdx.x >> 6;
    int kb = blockIdx.x & 63;
    int tid = threadIdx.x;

    __shared__ float xs[64][64];
    __shared__ float ws[64][65];

    const float* xp = x    + ((size_t)r * N_ + (size_t)kb * 64) * D_;
    const float* wp = fc_w + (size_t)r * D_ * D_;
    for (int i = 0; i < 16; ++i) {
        int flat = i * 256 + tid;
        xs[flat >> 6][flat & 63] = xp[flat];
        ws[flat >> 6][flat & 63] = wp[flat];
    }
    float coef = 0.f;
#pragma unroll
    for (int s = 0; s < S_; ++s) coef += theta[r * S_ + s] * tt[r * S_ + s];
    __syncthreads();

    int o = tid & 63, kg = tid >> 6;
    for (int kl = kg; kl < 64; kl += 4) {
        float dot = 0.f;
#pragma unroll
        for (int d = 0; d < D_; ++d) dot += xs[kl][d] * ws[o][d];
        ycombT[(size_t)(r * D_ + o) * N_ + (size_t)kb * 64 + kl] = f2bf(coef * dot);
    }
}

// Kernel 2: one block per (relation, 16-row slab). 4 waves split K (4 x 1024),
// LDS-reduce partials, bias + PReLU, write diffusions.
__global__ __launch_bounds__(256) void gemm_kernel(
    const float* __restrict__ a, const unsigned short* __restrict__ ycombT,
    const float* __restrict__ fc_b, const float* __restrict__ alpha0p,
    float* __restrict__ out) {
    int bid = blockIdx.x;             // 1024 blocks
    int r   = bid & 3;
    int rb  = bid >> 2;
    int w    = threadIdx.x >> 6;      // wave = K-chunk
    int lane = threadIdx.x & 63;
    int l15  = lane & 15;
    int kg   = lane >> 4;
    const int KC = N_ / 4;            // 1024 per wave

    const float* arow = a + ((size_t)(r * N_ + rb * 16 + l15)) * N_ + w * KC + kg * 8;
    const unsigned short* yb = ycombT + (size_t)r * D_ * N_ + w * KC + kg * 8;
    const unsigned short* b0 = yb + (size_t)(0 * 16 + l15) * N_;
    const unsigned short* b1 = yb + (size_t)(1 * 16 + l15) * N_;
    const unsigned short* b2 = yb + (size_t)(2 * 16 + l15) * N_;
    const unsigned short* b3 = yb + (size_t)(3 * 16 + l15) * N_;

    f32x4 acc0 = {0.f, 0.f, 0.f, 0.f};
    f32x4 acc1 = {0.f, 0.f, 0.f, 0.f};
    f32x4 acc2 = {0.f, 0.f, 0.f, 0.f};
    f32x4 acc3 = {0.f, 0.f, 0.f, 0.f};

#pragma unroll 4
    for (int k0 = 0; k0 < KC; k0 += 32) {
        float4 af0 = *(const float4*)(arow + k0);
        float4 af1 = *(const float4*)(arow + k0 + 4);
        bf16x8 afr;
        afr[0] = (short)f2bf(af0.x); afr[1] = (short)f2bf(af0.y);
        afr[2] = (short)f2bf(af0.z); afr[3] = (short)f2bf(af0.w);
        afr[4] = (short)f2bf(af1.x); afr[5] = (short)f2bf(af1.y);
        afr[6] = (short)f2bf(af1.z); afr[7] = (short)f2bf(af1.w);
        bf16x8 bv0 = *(const bf16x8*)(b0 + k0);
        bf16x8 bv1 = *(const bf16x8*)(b1 + k0);
        bf16x8 bv2 = *(const bf16x8*)(b2 + k0);
        bf16x8 bv3 = *(const bf16x8*)(b3 + k0);
        acc0 = __builtin_amdgcn_mfma_f32_16x16x32_bf16(afr, bv0, acc0, 0, 0, 0);
        acc1 = __builtin_amdgcn_mfma_f32_16x16x32_bf16(afr, bv1, acc1, 0, 0, 0);
        acc2 = __builtin_amdgcn_mfma_f32_16x16x32_bf16(afr, bv2, acc2, 0, 0, 0);
        acc3 = __builtin_amdgcn_mfma_f32_16x16x32_bf16(afr, bv3, acc3, 0, 0, 0);
    }

    // Cross-wave K-reduction in LDS. C/D layout: col=c*16+l15, row=kg*4+j (m89).
    __shared__ float red[R_][16][65];
#pragma unroll
    for (int c = 0; c < 4; ++c) {
        f32x4 acc = (c == 0) ? acc0 : (c == 1) ? acc1 : (c == 2) ? acc2 : acc3;
#pragma unroll
        for (int j = 0; j < 4; ++j)
            red[w][kg * 4 + j][c * 16 + l15] = acc[j];
    }
    __syncthreads();

    const float alpha0 = *alpha0p;
    const float* fcb = fc_b + r * D_;
    const size_t diff_off = (size_t)R_ * N_ * D_;     // out = [latent | diffusions]
    int t = threadIdx.x;
    int row = t >> 4, col0 = (t & 15) * 4;
    float4 v;
    float* vp = (float*)&v;
#pragma unroll
    for (int cc = 0; cc < 4; ++cc) {
        float s = red[0][row][col0 + cc] + red[1][row][col0 + cc]
                + red[2][row][col0 + cc] + red[3][row][col0 + cc] + fcb[col0 + cc];
        vp[cc] = (s >= 0.f) ? s : alpha0 * s;
    }
    *(float4*)(out + diff_off + ((size_t)(r * N_ + rb * 16 + row)) * D_ + col0) = v;
}

// Kernel 3: 1x1 conv over relation channels + PReLU.
__global__ __launch_bounds__(256) void conv_kernel(
    const float* __restrict__ conv_w, const float* __restrict__ conv_b,
    const float* __restrict__ alpha1p, float* __restrict__ out) {
    const size_t nd = (size_t)N_ * D_;
    const size_t diff_off = (size_t)R_ * nd;
    size_t i = ((size_t)blockIdx.x * 256 + threadIdx.x) * 4;   // float4 granularity

    float4 d0 = *(const float4*)(out + diff_off + 0 * nd + i);
    float4 d1 = *(const float4*)(out + diff_off + 1 * nd + i);
    float4 d2 = *(const float4*)(out + diff_off + 2 * nd + i);
    float4 d3 = *(const float4*)(out + diff_off + 3 * nd + i);
    const float alpha1 = *alpha1p;
#pragma unroll
    for (int s = 0; s < R_; ++s) {
        float w0 = conv_w[s * R_ + 0], w1 = conv_w[s * R_ + 1];
        float w2 = conv_w[s * R_ + 2], w3 = conv_w[s * R_ + 3];
        float cb = conv_b[s];
        float4 v;
        v.x = cb + w0 * d0.x + w1 * d1.x + w2 * d2.x + w3 * d3.x;
        v.y = cb + w0 * d0.y + w1 * d1.y + w2 * d2.y + w3 * d3.y;
        v.z = cb + w0 * d0.z + w1 * d1.z + w2 * d2.z + w3 * d3.z;
        v.w = cb + w0 * d0.w + w1 * d1.w + w2 * d2.w + w3 * d3.w;
        v.x = (v.x >= 0.f) ? v.x : alpha1 * v.x;
        v.y = (v.y >= 0.f) ? v.y : alpha1 * v.y;
        v.z = (v.z >= 0.f) ? v.z : alpha1 * v.z;
        v.w = (v.w >= 0.f) ? v.w : alpha1 * v.w;
        *(float4*)(out + s * nd + i) = v;
    }
}

extern "C" void kernel_launch(void* const* d_in, const int* in_sizes, int n_in,
                              void* d_out, int out_size, void* d_ws, size_t ws_size,
                              hipStream_t stream) {
    const float* theta  = (const float*)d_in[0];
    const float* tt     = (const float*)d_in[1];
    const float* a      = (const float*)d_in[2];
    const float* x      = (const float*)d_in[3];
    const float* fc_w   = (const float*)d_in[4];
    const float* fc_b   = (const float*)d_in[5];
    const float* conv_w = (const float*)d_in[6];
    const float* conv_b = (const float*)d_in[7];
    const float* alpha0 = (const float*)d_in[8];
    const float* alpha1 = (const float*)d_in[9];
    float* out = (float*)d_out;
    unsigned short* ycombT = (unsigned short*)d_ws;   // 2 MiB bf16

    prep_kernel<<<dim3(R_ * (N_ / 64)), dim3(256), 0, stream>>>(theta, tt, x, fc_w, ycombT);
    gemm_kernel<<<dim3((N_ / 16) * R_), dim3(256), 0, stream>>>(a, ycombT, fc_b, alpha0, out);
    conv_kernel<<<dim3((N_ * D_) / 4 / 256), dim3(256), 0, stream>>>(conv_w, conv_b, alpha1, out);
}